// Round 13
// baseline (48.468 us; speedup 1.0000x reference)
//
#include <hip/hip_runtime.h>
#include <hip/hip_bf16.h>
#include <math.h>

#define FDIM  128
#define BATCH 4096
#define CNUM  10000

typedef __attribute__((ext_vector_type(8))) short short8;   // 8 bf16 = 4 VGPRs (MFMA A/B frag)
typedef __attribute__((ext_vector_type(4))) float f32x4;    // MFMA C/D frag / float4 store

// ---------------- ws layout (bytes) ----------------
#define WS_FEATB 0            // 4096*128 bf16  = 1048576
#define WS_WB    1048576      // 10000*128 bf16 = 2560000
#define WS_F2    3608576      // 4096 f32
#define WS_W2    3624960      // 10000 f32
#define WS_COR   3664960      // 4096 f32

// exp(-m/1.8) = 2^(-m * C2);  C2 = 1/(1.8*ln2)
#define C2 0.80178372573096f

#define CGCLS 1280     // classes per class-group (8 groups x 1280 = 10240 >= CNUM)

// async global->LDS, 16B per lane, literal size
#define GL2LDS(g, l) __builtin_amdgcn_global_load_lds(                      \
    (const __attribute__((address_space(1))) void*)(g),                     \
    (__attribute__((address_space(3))) void*)(l), 16, 0, 0)

// Kernel 1: fused prep (f32->bf16 convert + row norms) and cor gather.
__global__ void prep_cor_kernel(const float* __restrict__ feat,
                                const float* __restrict__ weights,
                                const int* __restrict__ label,
                                __hip_bfloat16* __restrict__ featb,
                                __hip_bfloat16* __restrict__ wb,
                                float* __restrict__ f2,
                                float* __restrict__ w2,
                                float* __restrict__ cor) {
    int gw   = (blockIdx.x * blockDim.x + threadIdx.x) >> 6;
    int lane = threadIdx.x & 63;
    if (gw < BATCH + CNUM) {
        const float* src;
        __hip_bfloat16* dst;
        float* nrm;
        if (gw < BATCH) { src = feat    + (size_t)gw * FDIM; dst = featb + (size_t)gw * FDIM; nrm = f2 + gw; }
        else            { int r = gw - BATCH;
                          src = weights + (size_t)r  * FDIM; dst = wb    + (size_t)r  * FDIM; nrm = w2 + r; }
        float2 v = ((const float2*)src)[lane];
        __hip_bfloat162 b2;
        b2.x = __float2bfloat16(v.x);
        b2.y = __float2bfloat16(v.y);
        ((__hip_bfloat162*)dst)[lane] = b2;
        float ss = v.x * v.x + v.y * v.y;
        #pragma unroll
        for (int off = 32; off; off >>= 1) ss += __shfl_down(ss, off, 64);
        if (lane == 0) *nrm = ss;
    } else {
        int s = gw - (BATCH + CNUM);
        if (s >= BATCH) return;
        int lab = label[s];
        float2 f = ((const float2*)(feat    + (size_t)s   * FDIM))[lane];
        float2 w = ((const float2*)(weights + (size_t)lab * FDIM))[lane];
        float dx = f.x - w.x, dy = f.y - w.y;
        float ss = dx * dx + dy * dy;
        #pragma unroll
        for (int off = 32; off; off >>= 1) ss += __shfl_down(ss, off, 64);
        if (lane == 0) cor[s] = __expf(-ss * (1.0f / 1.8f));
    }
}

// Kernel 2: held-pair GEMM: 1024B-contiguous per-row store runs.
// 512 blocks x 512 thr, 2 blk/CU (LDS ~70KB, VGPR target <128).
// Block = band (64 rows, bx&63) x class-group cg (bx>>6): 10 contiguous
// tiles of 128 classes. Wave = 32 cls (aoff=(wid&3)*32) x 32 rows
// (boff=(wid>>2)*32): acc[2][2] + hold[2][2].
// Even t: compute tile t, epilogue -> HOLD in registers (no stores).
// Odd  t: compute tile t, store hold (tile t-1) + current -> per row the
// pair's classes are adjacent -> 1024B contiguous runs (R10 proved >=1KB
// runs eliminate write amplification; R6 measured 1.24x at 512B).
// A-LDS dbuf via GL2LDS + chunk-XOR swizzle; bfrag in VGPR; w2 slice in
// LDS; scale reduced in prologue.
// vmcnt (in-order retirement): pf(t+1) at top of iter t (4 ops/thread).
// End-of-iter wait: even t -> vmcnt(0) (drains pf + 1.5-iter-old stores);
// odd t -> vmcnt(8) (retires pf, keeps the 8 fresh stores in flight).
// Tail: masked stores only possible at t=9 (cg=7, cls>=10000) = last
// iter, after which no wait depends on the count. t=8 pf reads clamped.
__launch_bounds__(512, 4)
__global__ void gemm_kernel(const __hip_bfloat16* __restrict__ featb,
                            const __hip_bfloat16* __restrict__ wb,
                            const float* __restrict__ f2,
                            const float* __restrict__ w2,
                            const float* __restrict__ cor,
                            float* __restrict__ out) {
    __shared__ __align__(16) char lds[65536];    // A dbuf: buf0 | buf1
    __shared__ __align__(16) float w2l[CGCLS];
    __shared__ float red[8];

    int bx   = blockIdx.x;
    int band = bx & 63;            // 64 bands x 64 batch rows
    int cg   = bx >> 6;            // 8 class-groups x 1280 contiguous classes
    int tid  = threadIdx.x;
    int wid  = tid >> 6;
    int lane = tid & 63;
    int r16  = lane & 15;
    int kh   = lane >> 4;
    int aoff = (wid & 3) * 32;     // class strip within 128-tile
    int boff = (wid >> 2) * 32;    // row half within 64-band

    const char* Ab = (const char*)wb;
    const char* Bb = (const char*)featb;

    // ---- prologue ----
    #pragma unroll
    for (int p = 0; p < 4; ++p) {          // stage tile 0 into buf0
        int idx = tid + p * 512;
        int row = idx >> 4, chk = idx & 15;
        int gc = cg * CGCLS + row; gc = gc < CNUM ? gc : CNUM - 1;
        GL2LDS(Ab + (size_t)gc * 256 + (chk ^ (row & 7)) * 16, lds + idx * 16);
    }
    {   // deterministic cor reduction (identical in every block)
        float s = 0.0f;
        #pragma unroll
        for (int i = 0; i < BATCH / 512; ++i) s += cor[tid + i * 512];
        #pragma unroll
        for (int off = 32; off; off >>= 1) s += __shfl_down(s, off, 64);
        if (lane == 0) red[wid] = s;
    }
    #pragma unroll
    for (int p = 0; p < 3; ++p) {          // stage w2 slice (1280 f32)
        int idx = tid + p * 512;
        if (idx < CGCLS) {
            int cls = cg * CGCLS + idx;
            w2l[idx] = (cls < CNUM) ? w2[cls] : 0.0f;
        }
    }
    float f2n[2];
    short8 bfrag[4][2];
    #pragma unroll
    for (int n = 0; n < 2; ++n) {
        int rowg = band * 64 + boff + n * 16 + r16;
        f2n[n] = f2[rowg];
        #pragma unroll
        for (int kk = 0; kk < 4; ++kk)
            bfrag[kk][n] = *(const short8*)(Bb + (size_t)rowg * 256 + kk * 64 + kh * 16);
    }
    __syncthreads();   // full drain once (staging + red + w2l visible)

    float tot = 0.0f;
    #pragma unroll
    for (int i = 0; i < 8; ++i) tot += red[i];
    float avg = fmaxf(tot * (1.0f / BATCH), 0.5f);
    float ls2 = log2f(logf((float)(CNUM - 1)) / avg);

    f32x4 hold[2][2];              // even-tile results held for pair store

    #pragma unroll
    for (int t = 0; t < 10; ++t) {
        int cur = t & 1;

        // prefetch tile t+1 into the other buffer (safe: that buffer's
        // readers finished before the end-of-(t-1) barrier)
        if (t < 9) {
            #pragma unroll
            for (int p = 0; p < 4; ++p) {
                int idx = tid + p * 512;
                int row = idx >> 4, chk = idx & 15;
                int gc = cg * CGCLS + (t + 1) * 128 + row;
                gc = gc < CNUM ? gc : CNUM - 1;
                GL2LDS(Ab + (size_t)gc * 256 + (chk ^ (row & 7)) * 16,
                       lds + (cur ^ 1) * 32768 + idx * 16);
            }
        }
        __builtin_amdgcn_sched_barrier(0);   // pf issued before compute

        // ---- MFMA from current buffer ----
        const char* Abuf = lds + cur * 32768;
        f32x4 acc[2][2];
        #pragma unroll
        for (int mm = 0; mm < 2; ++mm)
            #pragma unroll
            for (int n = 0; n < 2; ++n) acc[mm][n] = (f32x4){0.f, 0.f, 0.f, 0.f};
        #pragma unroll
        for (int kk = 0; kk < 4; ++kk) {
            short8 a[2];
            #pragma unroll
            for (int mm = 0; mm < 2; ++mm) {
                int row = aoff + mm * 16 + r16;
                int c = (kk * 4 + kh) ^ (row & 7);
                a[mm] = *(const short8*)(Abuf + row * 256 + c * 16);
            }
            #pragma unroll
            for (int mm = 0; mm < 2; ++mm)
                #pragma unroll
                for (int n = 0; n < 2; ++n)
                    acc[mm][n] = __builtin_amdgcn_mfma_f32_16x16x32_bf16(a[mm], bfrag[kk][n], acc[mm][n], 0, 0, 0);
        }

        if ((t & 1) == 0) {
            // ---- even: epilogue -> hold (no stores) ----
            #pragma unroll
            for (int mm = 0; mm < 2; ++mm) {
                int lcl = t * 128 + aoff + mm * 16 + kh * 4;
                f32x4 w4 = *(const f32x4*)(&w2l[lcl]);
                #pragma unroll
                for (int n = 0; n < 2; ++n) {
                    f32x4 v;
                    #pragma unroll
                    for (int r = 0; r < 4; ++r) {
                        float mt2 = fmaf(-2.0f, acc[mm][n][r], f2n[n] + w4[r]);
                        mt2 = fmaxf(mt2, 0.0f);
                        v[r] = exp2f(fmaf(mt2, -C2, ls2));
                    }
                    hold[mm][n] = v;
                }
            }
        } else {
            // ---- odd: store hold (tile t-1) first, then current tile ----
            #pragma unroll
            for (int mm = 0; mm < 2; ++mm) {
                int cm0 = cg * CGCLS + (t - 1) * 128 + aoff + mm * 16 + kh * 4;
                bool ok = cm0 < CNUM;               // %4==0 -> no straddle
                #pragma unroll
                for (int n = 0; n < 2; ++n) {
                    if (ok) {
                        size_t rg = (size_t)(band * 64 + boff + n * 16 + r16);
                        *(f32x4*)(out + rg * CNUM + cm0) = hold[mm][n];
                    }
                }
            }
            #pragma unroll
            for (int mm = 0; mm < 2; ++mm) {
                int lcl = t * 128 + aoff + mm * 16 + kh * 4;
                int cm0 = cg * CGCLS + lcl;
                bool ok = cm0 < CNUM;
                f32x4 w4 = *(const f32x4*)(&w2l[lcl]);
                #pragma unroll
                for (int n = 0; n < 2; ++n) {
                    f32x4 v;
                    #pragma unroll
                    for (int r = 0; r < 4; ++r) {
                        float mt2 = fmaf(-2.0f, acc[mm][n][r], f2n[n] + w4[r]);
                        mt2 = fmaxf(mt2, 0.0f);
                        v[r] = exp2f(fmaf(mt2, -C2, ls2));
                    }
                    if (ok) {
                        size_t rg = (size_t)(band * 64 + boff + n * 16 + r16);
                        *(f32x4*)(out + rg * CNUM + cm0) = v;
                    }
                }
            }
        }

        // end-of-iter wait + barrier (skip after last iter)
        if (t < 9) {
            if ((t & 1) == 0) {
                // even: nothing issued after pf -> full drain retires pf
                // (also drains t-1's stores, which are 1.5 iters old)
                asm volatile("s_waitcnt vmcnt(0)" ::: "memory");
            } else {
                // odd: 8 stores issued after pf -> retire pf, keep stores
                asm volatile("s_waitcnt vmcnt(8)" ::: "memory");
            }
            __builtin_amdgcn_sched_barrier(0);
            __builtin_amdgcn_s_barrier();
        }
    }
}

extern "C" void kernel_launch(void* const* d_in, const int* in_sizes, int n_in,
                              void* d_out, int out_size, void* d_ws, size_t ws_size,
                              hipStream_t stream) {
    (void)in_sizes; (void)n_in; (void)out_size; (void)ws_size;
    const float* feat    = (const float*)d_in[0];
    const float* weights = (const float*)d_in[1];
    const int*   label   = (const int*)d_in[2];
    float* out = (float*)d_out;
    char*  ws  = (char*)d_ws;

    __hip_bfloat16* featb = (__hip_bfloat16*)(ws + WS_FEATB);
    __hip_bfloat16* wb    = (__hip_bfloat16*)(ws + WS_WB);
    float* f2  = (float*)(ws + WS_F2);
    float* w2  = (float*)(ws + WS_W2);
    float* cor = (float*)(ws + WS_COR);

    const int total_waves = BATCH + CNUM + BATCH;
    prep_cor_kernel<<<(total_waves + 3) / 4, 256, 0, stream>>>(
        feat, weights, label, featb, wb, f2, w2, cor);

    gemm_kernel<<<512, 512, 0, stream>>>(featb, wb, f2, w2, cor, out);
}

// Round 14
// 47.070 us; speedup vs baseline: 1.0297x; 1.0297x over previous
//
#include <hip/hip_runtime.h>
#include <hip/hip_bf16.h>
#include <math.h>

#define FDIM  128
#define BATCH 4096
#define CNUM  10000

typedef __attribute__((ext_vector_type(8))) short short8;   // 8 bf16 = 4 VGPRs (MFMA A/B frag)
typedef __attribute__((ext_vector_type(4))) float f32x4;    // MFMA C/D frag / float4 store

// ---------------- ws layout (bytes) ----------------
#define WS_FEATB 0            // 4096*128 bf16  = 1048576
#define WS_WB    1048576      // 10000*128 bf16 = 2560000
#define WS_F2    3608576      // 4096 f32
#define WS_W2    3624960      // 10000 f32
#define WS_COR   3664960      // 4096 f32

// exp(-m/1.8) = 2^(-m * C2);  C2 = 1/(1.8*ln2)
#define C2 0.80178372573096f

#define CGCLS 1280     // classes per class-group (8 groups x 1280 = 10240 >= CNUM)

// async global->LDS, 16B per lane, literal size
#define GL2LDS(g, l) __builtin_amdgcn_global_load_lds(                      \
    (const __attribute__((address_space(1))) void*)(g),                     \
    (__attribute__((address_space(3))) void*)(l), 16, 0, 0)

// Kernel 1: fused prep (f32->bf16 convert + row norms) and cor gather.
__global__ void prep_cor_kernel(const float* __restrict__ feat,
                                const float* __restrict__ weights,
                                const int* __restrict__ label,
                                __hip_bfloat16* __restrict__ featb,
                                __hip_bfloat16* __restrict__ wb,
                                float* __restrict__ f2,
                                float* __restrict__ w2,
                                float* __restrict__ cor) {
    int gw   = (blockIdx.x * blockDim.x + threadIdx.x) >> 6;
    int lane = threadIdx.x & 63;
    if (gw < BATCH + CNUM) {
        const float* src;
        __hip_bfloat16* dst;
        float* nrm;
        if (gw < BATCH) { src = feat    + (size_t)gw * FDIM; dst = featb + (size_t)gw * FDIM; nrm = f2 + gw; }
        else            { int r = gw - BATCH;
                          src = weights + (size_t)r  * FDIM; dst = wb    + (size_t)r  * FDIM; nrm = w2 + r; }
        float2 v = ((const float2*)src)[lane];
        __hip_bfloat162 b2;
        b2.x = __float2bfloat16(v.x);
        b2.y = __float2bfloat16(v.y);
        ((__hip_bfloat162*)dst)[lane] = b2;
        float ss = v.x * v.x + v.y * v.y;
        #pragma unroll
        for (int off = 32; off; off >>= 1) ss += __shfl_down(ss, off, 64);
        if (lane == 0) *nrm = ss;
    } else {
        int s = gw - (BATCH + CNUM);
        if (s >= BATCH) return;
        int lab = label[s];
        float2 f = ((const float2*)(feat    + (size_t)s   * FDIM))[lane];
        float2 w = ((const float2*)(weights + (size_t)lab * FDIM))[lane];
        float dx = f.x - w.x, dy = f.y - w.y;
        float ss = dx * dx + dy * dy;
        #pragma unroll
        for (int off = 32; off; off >>= 1) ss += __shfl_down(ss, off, 64);
        if (lane == 0) cor[s] = __expf(-ss * (1.0f / 1.8f));
    }
}

// Kernel 2: pair-hold GEMM with half-row-lagged stores, uniform vmcnt(4).
// 512 blocks x 512 thr, 2 blk/CU (LDS 69KB). Block = band (64 rows,
// bx&63) x class-group cg (bx>>6): 10 contiguous tiles of 128 classes.
// Wave = 32 cls (aoff=(wid&3)*32) x 32 rows (boff=(wid>>2)*32).
// Tile pair (e=2j, o=2j+1): results held in hold0 (even tile) / hold1
// (odd). Stores lag by row-half so EVERY iter has 4 stores after pf:
//   odd t : epilogue->hold1; store n=0 rows of (hold0,hold1)  [4 insts]
//   even t: store n=1 rows of previous pair (old hold0,hold1) [4 insts],
//           then epilogue->hold0 (overwrite after stores issued)
// Per row the full 1024B pair-run lands in one L2 window -> boundary-line
// write amplification 1.24 -> ~1.12 (R6/R10 mechanism), with NO vmcnt
// drains: outstanding at wait = [prev stores(4), pf(4), this stores(4)]
// -> vmcnt(4) retires pf + prev stores, keeps this iter's 4 in flight.
// A-LDS dbuf via GL2LDS + chunk-XOR swizzle; bfrag in VGPR; w2 in LDS;
// scale in prologue. Tail: t=9 no pf/wait; post-loop stores n=1 of last
// pair. Masked stores only in final pair (cg=7, cls>=10000) where no
// subsequent wait depends on counts.
__launch_bounds__(512, 4)
__global__ void gemm_kernel(const __hip_bfloat16* __restrict__ featb,
                            const __hip_bfloat16* __restrict__ wb,
                            const float* __restrict__ f2,
                            const float* __restrict__ w2,
                            const float* __restrict__ cor,
                            float* __restrict__ out) {
    __shared__ __align__(16) char lds[65536];    // A dbuf: buf0 | buf1
    __shared__ __align__(16) float w2l[CGCLS];
    __shared__ float red[8];

    int bx   = blockIdx.x;
    int band = bx & 63;            // 64 bands x 64 batch rows
    int cg   = bx >> 6;            // 8 class-groups x 1280 contiguous classes
    int tid  = threadIdx.x;
    int wid  = tid >> 6;
    int lane = tid & 63;
    int r16  = lane & 15;
    int kh   = lane >> 4;
    int aoff = (wid & 3) * 32;     // class strip within 128-tile
    int boff = (wid >> 2) * 32;    // row half within 64-band

    const char* Ab = (const char*)wb;
    const char* Bb = (const char*)featb;

    // ---- prologue ----
    #pragma unroll
    for (int p = 0; p < 4; ++p) {          // stage tile 0 into buf0
        int idx = tid + p * 512;
        int row = idx >> 4, chk = idx & 15;
        int gc = cg * CGCLS + row; gc = gc < CNUM ? gc : CNUM - 1;
        GL2LDS(Ab + (size_t)gc * 256 + (chk ^ (row & 7)) * 16, lds + idx * 16);
    }
    {   // deterministic cor reduction (identical in every block)
        float s = 0.0f;
        #pragma unroll
        for (int i = 0; i < BATCH / 512; ++i) s += cor[tid + i * 512];
        #pragma unroll
        for (int off = 32; off; off >>= 1) s += __shfl_down(s, off, 64);
        if (lane == 0) red[wid] = s;
    }
    #pragma unroll
    for (int p = 0; p < 3; ++p) {          // stage w2 slice (1280 f32)
        int idx = tid + p * 512;
        if (idx < CGCLS) {
            int cls = cg * CGCLS + idx;
            w2l[idx] = (cls < CNUM) ? w2[cls] : 0.0f;
        }
    }
    float f2n[2];
    short8 bfrag[4][2];
    #pragma unroll
    for (int n = 0; n < 2; ++n) {
        int rowg = band * 64 + boff + n * 16 + r16;
        f2n[n] = f2[rowg];
        #pragma unroll
        for (int kk = 0; kk < 4; ++kk)
            bfrag[kk][n] = *(const short8*)(Bb + (size_t)rowg * 256 + kk * 64 + kh * 16);
    }
    __syncthreads();   // full drain once (staging + red + w2l visible)

    float tot = 0.0f;
    #pragma unroll
    for (int i = 0; i < 8; ++i) tot += red[i];
    float avg = fmaxf(tot * (1.0f / BATCH), 0.5f);
    float ls2 = log2f(logf((float)(CNUM - 1)) / avg);

    f32x4 hold0[2][2];             // even-tile results (pair slot 0)
    f32x4 hold1[2][2];             // odd-tile results (pair slot 1)

    #pragma unroll
    for (int t = 0; t < 10; ++t) {
        int cur = t & 1;

        // prefetch tile t+1 into the other buffer
        if (t < 9) {
            #pragma unroll
            for (int p = 0; p < 4; ++p) {
                int idx = tid + p * 512;
                int row = idx >> 4, chk = idx & 15;
                int gc = cg * CGCLS + (t + 1) * 128 + row;
                gc = gc < CNUM ? gc : CNUM - 1;
                GL2LDS(Ab + (size_t)gc * 256 + (chk ^ (row & 7)) * 16,
                       lds + (cur ^ 1) * 32768 + idx * 16);
            }
        }
        __builtin_amdgcn_sched_barrier(0);   // pf issued before anything else

        // ---- MFMA from current buffer ----
        const char* Abuf = lds + cur * 32768;
        f32x4 acc[2][2];
        #pragma unroll
        for (int mm = 0; mm < 2; ++mm)
            #pragma unroll
            for (int n = 0; n < 2; ++n) acc[mm][n] = (f32x4){0.f, 0.f, 0.f, 0.f};
        #pragma unroll
        for (int kk = 0; kk < 4; ++kk) {
            short8 a[2];
            #pragma unroll
            for (int mm = 0; mm < 2; ++mm) {
                int row = aoff + mm * 16 + r16;
                int c = (kk * 4 + kh) ^ (row & 7);
                a[mm] = *(const short8*)(Abuf + row * 256 + c * 16);
            }
            #pragma unroll
            for (int mm = 0; mm < 2; ++mm)
                #pragma unroll
                for (int n = 0; n < 2; ++n)
                    acc[mm][n] = __builtin_amdgcn_mfma_f32_16x16x32_bf16(a[mm], bfrag[kk][n], acc[mm][n], 0, 0, 0);
        }

        if ((t & 1) == 0) {
            // ---- even t: store n=1 rows of PREVIOUS pair (t-2, t-1) ----
            if (t >= 2) {
                #pragma unroll
                for (int mm = 0; mm < 2; ++mm) {
                    int c0 = cg * CGCLS + (t - 2) * 128 + aoff + mm * 16 + kh * 4;
                    int c1 = c0 + 128;
                    size_t rg = (size_t)(band * 64 + boff + 16 + r16);
                    if (c0 < CNUM) *(f32x4*)(out + rg * CNUM + c0) = hold0[mm][1];
                    if (c1 < CNUM) *(f32x4*)(out + rg * CNUM + c1) = hold1[mm][1];
                }
            }
            // epilogue -> hold0 (after old hold0's stores are issued)
            #pragma unroll
            for (int mm = 0; mm < 2; ++mm) {
                int lcl = t * 128 + aoff + mm * 16 + kh * 4;
                f32x4 w4 = *(const f32x4*)(&w2l[lcl]);
                #pragma unroll
                for (int n = 0; n < 2; ++n) {
                    f32x4 v;
                    #pragma unroll
                    for (int r = 0; r < 4; ++r) {
                        float mt2 = fmaf(-2.0f, acc[mm][n][r], f2n[n] + w4[r]);
                        mt2 = fmaxf(mt2, 0.0f);
                        v[r] = exp2f(fmaf(mt2, -C2, ls2));
                    }
                    hold0[mm][n] = v;
                }
            }
        } else {
            // ---- odd t: epilogue -> hold1, then store n=0 of (t-1, t) ----
            #pragma unroll
            for (int mm = 0; mm < 2; ++mm) {
                int lcl = t * 128 + aoff + mm * 16 + kh * 4;
                f32x4 w4 = *(const f32x4*)(&w2l[lcl]);
                #pragma unroll
                for (int n = 0; n < 2; ++n) {
                    f32x4 v;
                    #pragma unroll
                    for (int r = 0; r < 4; ++r) {
                        float mt2 = fmaf(-2.0f, acc[mm][n][r], f2n[n] + w4[r]);
                        mt2 = fmaxf(mt2, 0.0f);
                        v[r] = exp2f(fmaf(mt2, -C2, ls2));
                    }
                    hold1[mm][n] = v;
                }
            }
            #pragma unroll
            for (int mm = 0; mm < 2; ++mm) {
                int c0 = cg * CGCLS + (t - 1) * 128 + aoff + mm * 16 + kh * 4;
                int c1 = c0 + 128;
                size_t rg = (size_t)(band * 64 + boff + r16);
                if (c0 < CNUM) *(f32x4*)(out + rg * CNUM + c0) = hold0[mm][0];
                if (c1 < CNUM) *(f32x4*)(out + rg * CNUM + c1) = hold1[mm][0];
            }
        }

        // uniform counted wait: retire pf (+1-iter-old stores), keep this
        // iter's 4 stores in flight. t=0 has no stores -> full drain (free).
        if (t < 9) {
            if (t == 0) asm volatile("s_waitcnt vmcnt(0)" ::: "memory");
            else        asm volatile("s_waitcnt vmcnt(4)" ::: "memory");
            __builtin_amdgcn_sched_barrier(0);
            __builtin_amdgcn_s_barrier();
        }
    }

    // ---- tail: n=1 rows of the last pair (tiles 8,9) ----
    #pragma unroll
    for (int mm = 0; mm < 2; ++mm) {
        int c0 = cg * CGCLS + 8 * 128 + aoff + mm * 16 + kh * 4;
        int c1 = c0 + 128;
        size_t rg = (size_t)(band * 64 + boff + 16 + r16);
        if (c0 < CNUM) *(f32x4*)(out + rg * CNUM + c0) = hold0[mm][1];
        if (c1 < CNUM) *(f32x4*)(out + rg * CNUM + c1) = hold1[mm][1];
    }
}

extern "C" void kernel_launch(void* const* d_in, const int* in_sizes, int n_in,
                              void* d_out, int out_size, void* d_ws, size_t ws_size,
                              hipStream_t stream) {
    (void)in_sizes; (void)n_in; (void)out_size; (void)ws_size;
    const float* feat    = (const float*)d_in[0];
    const float* weights = (const float*)d_in[1];
    const int*   label   = (const int*)d_in[2];
    float* out = (float*)d_out;
    char*  ws  = (char*)d_ws;

    __hip_bfloat16* featb = (__hip_bfloat16*)(ws + WS_FEATB);
    __hip_bfloat16* wb    = (__hip_bfloat16*)(ws + WS_WB);
    float* f2  = (float*)(ws + WS_F2);
    float* w2  = (float*)(ws + WS_W2);
    float* cor = (float*)(ws + WS_COR);

    const int total_waves = BATCH + CNUM + BATCH;
    prep_cor_kernel<<<(total_waves + 3) / 4, 256, 0, stream>>>(
        feat, weights, label, featb, wb, f2, w2, cor);

    gemm_kernel<<<512, 512, 0, stream>>>(featb, wb, f2, w2, cor, out);
}